// Round 15
// baseline (221.460 us; speedup 1.0000x reference)
//
#include <hip/hip_runtime.h>

#define NN 100000
#define NB 256            // buckets
#define NPB 391           // nodes per bucket: ceil(100000/256)=391; local dst fits in 9 bits
#define MSCH 4096         // edges per block for hist/scatter
#define NBLK 782          // ceil(3200000/4096); recomputed at launch for safety

__device__ inline unsigned short f2bf(float f) {
    unsigned u = __float_as_uint(f);
    return (unsigned short)((u + 0x7FFFu + ((u >> 16) & 1u)) >> 16);
}
__device__ inline unsigned packbf(float a, float b) {
    return (unsigned)f2bf(a) | ((unsigned)f2bf(b) << 16);
}
__device__ inline float bflo(unsigned u) { return __uint_as_float(u << 16); }
__device__ inline float bfhi(unsigned u) { return __uint_as_float(u & 0xFFFF0000u); }
__device__ inline float4 bf4(uint2 u) {
    return make_float4(bflo(u.x), bfhi(u.x), bflo(u.y), bfhi(u.y));
}

// ---- fp8 e4m3 (hardware cvt; encode+decode same HW format -> consistent) ----
__device__ inline void fp8acc(unsigned u, float4& a) {
    auto lo = __builtin_amdgcn_cvt_pk_f32_fp8((int)u, false);
    auto hi = __builtin_amdgcn_cvt_pk_f32_fp8((int)u, true);
    a.x += lo[0]; a.y += lo[1]; a.z += hi[0]; a.w += hi[1];
}
__device__ inline unsigned char f2fp8(float v) {
    return (unsigned char)(__builtin_amdgcn_cvt_pk_fp8_f32(v, 0.f, 0, false) & 0xFF);
}
__device__ inline unsigned short f2fp8x2(float a, float b) {
    return (unsigned short)(__builtin_amdgcn_cvt_pk_fp8_f32(a, b, 0, false) & 0xFFFF);
}

typedef __attribute__((ext_vector_type(8))) short bf16x8;
typedef __attribute__((ext_vector_type(4))) float f32x4;

// ---------------- CSR build: atomic-free 3-pass radix partition ----------------

// pass A: per-block bucket histogram -> counts[blk][NB] (coalesced plain writes, no global atomics)
__global__ __launch_bounds__(256) void histA_kernel(const int* __restrict__ dst, int E,
                                                    int* __restrict__ counts) {
    __shared__ int h[NB];
    int t = threadIdx.x, blk = blockIdx.x;
    h[t] = 0;
    __syncthreads();
    long c0 = (long)blk * MSCH;
    int nE = (int)min((long)MSCH, E - c0);
    for (int k = t; k < nE; k += 256)
        atomicAdd(&h[dst[c0 + k] / NPB], 1);
    __syncthreads();
    counts[(size_t)blk * NB + t] = h[t];
}

// pass B1: per-bucket exclusive scan across blocks. Block b scans counts[*][b] (nblk entries),
// writes blkoff[*][b] (exclusive) and totals[b].
__global__ __launch_bounds__(256) void bscan2_kernel(const int* __restrict__ counts, int nblk,
                                                     int* __restrict__ blkoff, int* __restrict__ totals) {
    int b = blockIdx.x, t = threadIdx.x;
    const int NP = 4;                 // ceil(nblk/256) for nblk<=1024
    int c[NP];
    int s = 0;
    #pragma unroll
    for (int q = 0; q < NP; ++q) {
        int j = t * NP + q;
        c[q] = (j < nblk) ? counts[(size_t)j * NB + b] : 0;
        s += c[q];
    }
    __shared__ int sh[256];
    sh[t] = s;
    __syncthreads();
    for (int off = 1; off < 256; off <<= 1) {
        int u = (t >= off) ? sh[t - off] : 0;
        __syncthreads();
        sh[t] += u;
        __syncthreads();
    }
    int base = sh[t] - s;             // exclusive over thread groups
    int run = base;
    #pragma unroll
    for (int q = 0; q < NP; ++q) {
        int j = t * NP + q;
        if (j < nblk) blkoff[(size_t)j * NB + b] = run;
        run += c[q];
    }
    if (t == 255) totals[b] = sh[255];
}

// pass B2: 1-block exclusive scan of bucket totals -> bstart
__global__ __launch_bounds__(NB) void bstart_kernel(const int* __restrict__ totals, int* __restrict__ bstart, int E) {
    __shared__ int sh[NB];
    int t = threadIdx.x;
    int v = totals[t];
    sh[t] = v;
    __syncthreads();
    for (int off = 1; off < NB; off <<= 1) {
        int u = (t >= off) ? sh[t - off] : 0;
        __syncthreads();
        sh[t] += u;
        __syncthreads();
    }
    bstart[t] = sh[t] - v;
    if (t == NB - 1) bstart[NB] = E;
}

// pass C: scatter packed (src<<9 | ld) to dense bucket regions; bases from bstart+blkoff (LDS atomics only)
__global__ __launch_bounds__(256) void scatter_kernel(const int* __restrict__ src, const int* __restrict__ dst,
                                                      int E, const int* __restrict__ bstart,
                                                      const int* __restrict__ blkoff,
                                                      unsigned int* __restrict__ packed) {
    __shared__ int base[NB];
    int t = threadIdx.x, blk = blockIdx.x;
    base[t] = bstart[t] + blkoff[(size_t)blk * NB + t];
    __syncthreads();
    long c0 = (long)blk * MSCH;
    int nE = (int)min((long)MSCH, E - c0);
    for (int k = t; k < nE; k += 256) {
        int d = dst[c0 + k];
        int s = src[c0 + k];
        int b = d / NPB;
        int ld = d - b * NPB;
        int pos = atomicAdd(&base[b], 1);
        packed[pos] = ((unsigned)s << 9) | (unsigned)ld;
    }
}

// one block (512 thr) per bucket: LDS hist+scan over NPB local nodes -> rowptr/dinv, cursor fill -> col
__global__ __launch_bounds__(512) void bucket_fill_kernel(const unsigned int* __restrict__ packed,
                                                          const int* __restrict__ bstart, int N, int E,
                                                          int* __restrict__ rowptr, int* __restrict__ col,
                                                          float* __restrict__ dinv) {
    int b = blockIdx.x, t = threadIdx.x;
    int e0 = bstart[b], cnt = bstart[b + 1] - e0;
    __shared__ int hist[512];
    __shared__ int sh[512];
    __shared__ int cur[512];
    hist[t] = 0;
    __syncthreads();
    for (int e = t; e < cnt; e += 512)
        atomicAdd(&hist[packed[e0 + e] & 511u], 1);
    __syncthreads();
    int v = hist[t];
    sh[t] = v;
    __syncthreads();
    for (int off = 1; off < 512; off <<= 1) {
        int u = (t >= off) ? sh[t - off] : 0;
        __syncthreads();
        sh[t] += u;
        __syncthreads();
    }
    int ex = sh[t] - v;
    int node = b * NPB + t;
    if (t < NPB && node < N) {
        rowptr[node] = e0 + ex;
        dinv[node] = rsqrtf(1.0f + (float)v);
    }
    cur[t] = e0 + ex;
    __syncthreads();
    for (int e = t; e < cnt; e += 512) {
        unsigned int p = packed[e0 + e];
        int pos = atomicAdd(&cur[p & 511u], 1);
        col[pos] = (int)(p >> 9);
    }
    if (b == 0 && t == 0) rowptr[N] = E;
}

// ---------------- layer-1 weight prepack: Wpk[c][k] = bf16(W^T) ----

__global__ __launch_bounds__(256) void wpack_kernel(const float* __restrict__ W1, const float* __restrict__ Ws02,
                                                    const float* __restrict__ Ws03, unsigned short* __restrict__ Wpk) {
    int i = blockIdx.x * 256 + threadIdx.x;
    if (i >= 112 * 128) return;
    int c = i >> 7, k = i & 127;
    float v;
    if (c < 64)      v = W1[k * 64 + c];
    else if (c < 96) v = Ws02[k * 32 + (c - 64)];
    else             v = Ws03[k * 16 + (c - 96)];
    Wpk[i] = f2bf(v);
}

// ---------------- mfma3: one x pass -> hs1 ([N][64] fp8, scaled), s02 (32, bias, bf16), s03 (16, bias, bf16) ----
// 2 row-tiles per wave (32 rows) sharing B-fragments.

__global__ __launch_bounds__(256) void mfma3_kernel(const float* __restrict__ X,
        const unsigned short* __restrict__ Wpk, const float* __restrict__ scale,
        const float* __restrict__ bb, const float* __restrict__ bc,
        unsigned char* __restrict__ oa, unsigned short* __restrict__ ob,
        unsigned short* __restrict__ oc, int N) {
    int t = threadIdx.x;
    int wv = t >> 6, l = t & 63;
    int r0 = blockIdx.x * 128 + wv * 32;
    int col = l & 15, g = l >> 4;
    int rowA0 = r0 + col, rowA1 = r0 + 16 + col;
    bool ok0 = rowA0 < N, ok1 = rowA1 < N;
    const float* xr0 = X + (size_t)rowA0 * 128;
    const float* xr1 = X + (size_t)rowA1 * 128;

    f32x4 acc[2][7];
    #pragma unroll
    for (int ti = 0; ti < 2; ++ti)
        #pragma unroll
        for (int i = 0; i < 7; ++i) acc[ti][i] = (f32x4){0.f, 0.f, 0.f, 0.f};

    #pragma unroll
    for (int s = 0; s < 4; ++s) {
        int k0 = s * 32 + g * 8;
        float4 lo0 = ok0 ? *(const float4*)(xr0 + k0)     : make_float4(0.f, 0.f, 0.f, 0.f);
        float4 hi0 = ok0 ? *(const float4*)(xr0 + k0 + 4) : make_float4(0.f, 0.f, 0.f, 0.f);
        float4 lo1 = ok1 ? *(const float4*)(xr1 + k0)     : make_float4(0.f, 0.f, 0.f, 0.f);
        float4 hi1 = ok1 ? *(const float4*)(xr1 + k0 + 4) : make_float4(0.f, 0.f, 0.f, 0.f);
        union { bf16x8 v; unsigned u[4]; } A0, A1;
        A0.u[0] = packbf(lo0.x, lo0.y); A0.u[1] = packbf(lo0.z, lo0.w);
        A0.u[2] = packbf(hi0.x, hi0.y); A0.u[3] = packbf(hi0.z, hi0.w);
        A1.u[0] = packbf(lo1.x, lo1.y); A1.u[1] = packbf(lo1.z, lo1.w);
        A1.u[2] = packbf(hi1.x, hi1.y); A1.u[3] = packbf(hi1.z, hi1.w);
        #pragma unroll
        for (int ct = 0; ct < 7; ++ct) {
            bf16x8 B = *(const bf16x8*)(Wpk + ((size_t)(ct * 16 + col) * 128 + k0));
            acc[0][ct] = __builtin_amdgcn_mfma_f32_16x16x32_bf16(A0.v, B, acc[0][ct], 0, 0, 0);
            acc[1][ct] = __builtin_amdgcn_mfma_f32_16x16x32_bf16(A1.v, B, acc[1][ct], 0, 0, 0);
        }
    }

    #pragma unroll
    for (int ti = 0; ti < 2; ++ti) {
        #pragma unroll
        for (int v = 0; v < 4; ++v) {
            int row = r0 + ti * 16 + g * 4 + v;
            if (row < N) {
                float sc = scale[row];
                #pragma unroll
                for (int ct = 0; ct < 4; ++ct)
                    oa[(size_t)row * 64 + ct * 16 + col] = f2fp8(acc[ti][ct][v] * sc);
                #pragma unroll
                for (int ct = 4; ct < 6; ++ct) {
                    int c2 = (ct - 4) * 16 + col;
                    ob[(size_t)row * 32 + c2] = f2bf(acc[ti][ct][v] + bb[c2]);
                }
                oc[(size_t)row * 16 + col] = f2bf(acc[ti][6][v] + bc[col]);
            }
        }
    }
}

// ---------------- gemm2b: bf16 X input -> hs2 (fp8, scaled), s13 (bf16, bias) ----------------

template <int K, int C1, int C2>
__global__ __launch_bounds__(256) void gemm2b_kernel(const unsigned short* __restrict__ X,
        const float* __restrict__ Wa, const float* __restrict__ scale,
        const float* __restrict__ Wb, const float* __restrict__ bb,
        unsigned char* __restrict__ oa, unsigned short* __restrict__ ob, int N) {
    constexpr int M1 = C1 / 16, M2 = C2 / 16;
    constexpr int XS = K + 6;
    __shared__ float XL[64 * XS];
    __shared__ float WLa[K * C1];
    __shared__ float WLb[K * C2];
    int t = threadIdx.x;
    int r0 = blockIdx.x * 64;

    for (int i = t; i < K * C1 / 4; i += 256) ((float4*)WLa)[i] = ((const float4*)Wa)[i];
    for (int i = t; i < K * C2 / 4; i += 256) ((float4*)WLb)[i] = ((const float4*)Wb)[i];
    for (int i = t; i < 64 * (K / 4); i += 256) {
        int row = i / (K / 4), g = i % (K / 4);
        uint2 u = make_uint2(0u, 0u);
        if (r0 + row < N) u = ((const uint2*)(X + (size_t)(r0 + row) * K))[g];
        float* p = &XL[row * XS + g * 4];
        *(float2*)p = make_float2(bflo(u.x), bfhi(u.x));
        *(float2*)(p + 2) = make_float2(bflo(u.y), bfhi(u.y));
    }
    __syncthreads();

    int ty = t >> 4, tx = t & 15;
    float acc1[4][M1] = {}, acc2[4][M2] = {};
    const float* xb = &XL[(ty * 4) * XS];
    const float* wba = &WLa[tx * M1];
    const float* wbb = &WLb[tx * M2];
    for (int k = 0; k < K; ++k) {
        float x0 = xb[k], x1 = xb[XS + k], x2 = xb[2 * XS + k], x3 = xb[3 * XS + k];
        float wa[M1], wb2[M2];
        #pragma unroll
        for (int j = 0; j < M1; ++j) wa[j] = wba[k * C1 + j];
        #pragma unroll
        for (int j = 0; j < M2; ++j) wb2[j] = wbb[k * C2 + j];
        #pragma unroll
        for (int j = 0; j < M1; ++j) {
            acc1[0][j] = fmaf(x0, wa[j], acc1[0][j]);
            acc1[1][j] = fmaf(x1, wa[j], acc1[1][j]);
            acc1[2][j] = fmaf(x2, wa[j], acc1[2][j]);
            acc1[3][j] = fmaf(x3, wa[j], acc1[3][j]);
        }
        #pragma unroll
        for (int j = 0; j < M2; ++j) {
            acc2[0][j] = fmaf(x0, wb2[j], acc2[0][j]);
            acc2[1][j] = fmaf(x1, wb2[j], acc2[1][j]);
            acc2[2][j] = fmaf(x2, wb2[j], acc2[2][j]);
            acc2[3][j] = fmaf(x3, wb2[j], acc2[3][j]);
        }
    }

    #pragma unroll
    for (int i = 0; i < 4; ++i) {
        int row = r0 + ty * 4 + i;
        if (row < N) {
            float sc = scale[row];
            *(unsigned short*)(oa + (size_t)row * C1 + tx * 2) = f2fp8x2(acc1[i][0] * sc, acc1[i][1] * sc);
            ob[(size_t)row * C2 + tx] = f2bf(acc2[i][0] + bb[tx]);
        }
    }
}

// ---------------- gemm_l3: bf16 X [N][32] -> hs3 [N][16] fp8, scaled ----------------

__global__ __launch_bounds__(256) void gemm_l3_kernel(const unsigned short* __restrict__ X,
        const float* __restrict__ W, const float* __restrict__ scale,
        unsigned char* __restrict__ out, int N) {
    constexpr int K = 32, C = 16, XS = K + 6;
    __shared__ float XL[64 * XS];
    __shared__ float WL[K * C];
    int t = threadIdx.x;
    int r0 = blockIdx.x * 64;

    for (int i = t; i < K * C / 4; i += 256) ((float4*)WL)[i] = ((const float4*)W)[i];
    for (int i = t; i < 64 * (K / 4); i += 256) {
        int row = i / (K / 4), g = i % (K / 4);
        uint2 u = make_uint2(0u, 0u);
        if (r0 + row < N) u = ((const uint2*)(X + (size_t)(r0 + row) * K))[g];
        float* p = &XL[row * XS + g * 4];
        *(float2*)p = make_float2(bflo(u.x), bfhi(u.x));
        *(float2*)(p + 2) = make_float2(bflo(u.y), bfhi(u.y));
    }
    __syncthreads();

    int ty = t >> 4, tx = t & 15;
    float acc[4] = {0.f, 0.f, 0.f, 0.f};
    const float* xb = &XL[(ty * 4) * XS];
    for (int k = 0; k < K; ++k) {
        float wv = WL[k * C + tx];
        acc[0] = fmaf(xb[k], wv, acc[0]);
        acc[1] = fmaf(xb[XS + k], wv, acc[1]);
        acc[2] = fmaf(xb[2 * XS + k], wv, acc[2]);
        acc[3] = fmaf(xb[3 * XS + k], wv, acc[3]);
    }
    #pragma unroll
    for (int i = 0; i < 4; ++i) {
        int row = r0 + ty * 4 + i;
        if (row < N) out[(size_t)row * C + tx] = f2fp8(acc[i] * scale[row]);
    }
}

// ---------------- Aggregation (fp8 hs gather) ----------------

template <int F, int FPL, bool OBF>
__global__ __launch_bounds__(256) void agg_kernel(const unsigned char* __restrict__ hs,
        const int* __restrict__ rowptr, const int* __restrict__ col,
        const float* __restrict__ dinv, const float* __restrict__ bias,
        const unsigned short* __restrict__ skipA, const unsigned short* __restrict__ skipB,
        void* __restrict__ outv, int N) {
    constexpr int VL = F / FPL;
    constexpr int NPW = 64 / VL;
    constexpr int W = 8;
    constexpr int CR = W / VL;
    int t = threadIdx.x;
    int lane = t & 63, wv = t >> 6;
    int sub = lane / VL, fq = lane % VL;
    int i = (blockIdx.x * 4 + wv) * NPW + sub;
    if (i >= N) return;

    float4 aA0 = make_float4(0.f, 0.f, 0.f, 0.f);
    float4 aA1 = make_float4(0.f, 0.f, 0.f, 0.f);
    float4 aB0 = make_float4(0.f, 0.f, 0.f, 0.f);
    float4 aB1 = make_float4(0.f, 0.f, 0.f, 0.f);

    {
        const unsigned char* hrow = hs + (size_t)i * F + fq * FPL;
        if constexpr (FPL == 8) {
            uint2 u = *(const uint2*)hrow;
            fp8acc(u.x, aA0); fp8acc(u.y, aB0);
        } else {
            fp8acc(*(const unsigned*)hrow, aA0);
        }
    }

    int p0 = rowptr[i], p1 = rowptr[i + 1];
    int p = p0;
    for (; p + W <= p1; p += W) {
        int cw[CR];
        #pragma unroll
        for (int j = 0; j < CR; ++j) cw[j] = col[p + fq + j * VL];
        #pragma unroll
        for (int k = 0; k < W; ++k) {
            int s = __shfl(cw[k / VL], k % VL, VL);
            const unsigned char* sp = hs + (size_t)s * F + fq * FPL;
            if constexpr (FPL == 8) {
                uint2 u = *(const uint2*)sp;
                if (k & 1) { fp8acc(u.x, aA1); fp8acc(u.y, aB1); }
                else       { fp8acc(u.x, aA0); fp8acc(u.y, aB0); }
            } else {
                if (k & 1) fp8acc(*(const unsigned*)sp, aA1);
                else       fp8acc(*(const unsigned*)sp, aA0);
            }
        }
    }
    for (; p < p1; p += VL) {
        int c = (p + fq < p1) ? col[p + fq] : 0;
        int m = min(VL, p1 - p);
        for (int k = 0; k < m; ++k) {
            int s = __shfl(c, k, VL);
            const unsigned char* sp = hs + (size_t)s * F + fq * FPL;
            if constexpr (FPL == 8) {
                uint2 u = *(const uint2*)sp;
                fp8acc(u.x, aA1); fp8acc(u.y, aB1);
            } else {
                fp8acc(*(const unsigned*)sp, aA1);
            }
        }
    }

    float di = dinv[i];
    int fb = fq * FPL;
    float o[FPL];
    o[0] = fmaxf(di * (aA0.x + aA1.x) + bias[fb + 0], 0.f);
    o[1] = fmaxf(di * (aA0.y + aA1.y) + bias[fb + 1], 0.f);
    o[2] = fmaxf(di * (aA0.z + aA1.z) + bias[fb + 2], 0.f);
    o[3] = fmaxf(di * (aA0.w + aA1.w) + bias[fb + 3], 0.f);
    if constexpr (FPL == 8) {
        o[4] = fmaxf(di * (aB0.x + aB1.x) + bias[fb + 4], 0.f);
        o[5] = fmaxf(di * (aB0.y + aB1.y) + bias[fb + 5], 0.f);
        o[6] = fmaxf(di * (aB0.z + aB1.z) + bias[fb + 6], 0.f);
        o[7] = fmaxf(di * (aB0.w + aB1.w) + bias[fb + 7], 0.f);
    }
    if (skipA) {
        const unsigned short* sp = skipA + (size_t)i * F + fb;
        if constexpr (FPL == 8) {
            uint4 sa = *(const uint4*)sp;
            float4 s0 = bf4(make_uint2(sa.x, sa.y)), s1 = bf4(make_uint2(sa.z, sa.w));
            o[0] += s0.x; o[1] += s0.y; o[2] += s0.z; o[3] += s0.w;
            o[4] += s1.x; o[5] += s1.y; o[6] += s1.z; o[7] += s1.w;
        } else {
            float4 s0 = bf4(*(const uint2*)sp);
            o[0] += s0.x; o[1] += s0.y; o[2] += s0.z; o[3] += s0.w;
        }
    }
    if (skipB) {
        const unsigned short* sp = skipB + (size_t)i * F + fb;
        if constexpr (FPL == 8) {
            uint4 sa = *(const uint4*)sp;
            float4 s0 = bf4(make_uint2(sa.x, sa.y)), s1 = bf4(make_uint2(sa.z, sa.w));
            o[0] += s0.x; o[1] += s0.y; o[2] += s0.z; o[3] += s0.w;
            o[4] += s1.x; o[5] += s1.y; o[6] += s1.z; o[7] += s1.w;
        } else {
            float4 s0 = bf4(*(const uint2*)sp);
            o[0] += s0.x; o[1] += s0.y; o[2] += s0.z; o[3] += s0.w;
        }
    }

    if constexpr (OBF) {
        unsigned short* op = (unsigned short*)outv + (size_t)i * F + fb;
        if constexpr (FPL == 8) {
            uint4 w4;
            w4.x = packbf(o[0], o[1]); w4.y = packbf(o[2], o[3]);
            w4.z = packbf(o[4], o[5]); w4.w = packbf(o[6], o[7]);
            *(uint4*)op = w4;
        } else {
            uint2 w2;
            w2.x = packbf(o[0], o[1]); w2.y = packbf(o[2], o[3]);
            *(uint2*)op = w2;
        }
    } else {
        *(float4*)((float*)outv + (size_t)i * F + fb) = make_float4(o[0], o[1], o[2], o[3]);
    }
}

// ---------------- launch ----------------

extern "C" void kernel_launch(void* const* d_in, const int* in_sizes, int n_in,
                              void* d_out, int out_size, void* d_ws, size_t ws_size,
                              hipStream_t stream) {
    const int N = NN;
    const float* x   = (const float*)d_in[0];
    const int*   ei  = (const int*)d_in[1];
    const int    E   = in_sizes[1] / 2;
    const int*   src = ei;
    const int*   dst = ei + E;
    const float* W1 = (const float*)d_in[2],  *b1  = (const float*)d_in[3];
    const float* W2 = (const float*)d_in[4],  *b2  = (const float*)d_in[5];
    const float* W3 = (const float*)d_in[6],  *b3  = (const float*)d_in[7];
    const float* Ws02 = (const float*)d_in[8],  *bs02 = (const float*)d_in[9];
    const float* Ws03 = (const float*)d_in[10], *bs03 = (const float*)d_in[11];
    const float* Ws13 = (const float*)d_in[12], *bs13 = (const float*)d_in[13];

    const int nblk = (E + MSCH - 1) / MSCH;   // 782 for E=3.2M

    char* w = (char*)d_ws;
    size_t off = 0;
    auto alloc = [&](size_t bytes) -> void* {
        void* p = w + off;
        off += (bytes + 255) & ~(size_t)255;
        return p;
    };
    int*   bstart   = (int*)alloc((size_t)(NB + 1) * 4);
    int*   totals   = (int*)alloc((size_t)NB * 4);
    int*   rowptr   = (int*)alloc(((size_t)N + 1) * 4);
    float* dinv     = (float*)alloc((size_t)N * 4);
    int*   col      = (int*)alloc((size_t)E * 4);
    int*   counts   = (int*)alloc((size_t)nblk * NB * 4);   // 800 KB
    int*   blkoff   = (int*)alloc((size_t)nblk * NB * 4);   // 800 KB
    unsigned short* Wpk = (unsigned short*)alloc((size_t)112 * 128 * 2);
    unsigned char* hs1  = (unsigned char*)alloc((size_t)N * 64 * 2);    // fp8 [N][64] in first N*64 bytes
    unsigned short* x1  = (unsigned short*)alloc((size_t)N * 64 * 2);   // bf16 [N][64]
    unsigned short* s02 = (unsigned short*)alloc((size_t)N * 32 * 2);   // bf16 [N][32]
    unsigned short* s03 = (unsigned short*)alloc((size_t)N * 16 * 2);   // bf16 [N][16]
    unsigned short* x2  = (unsigned short*)alloc((size_t)N * 32 * 2);   // bf16 [N][32]
    // aliases over dead regions
    unsigned int* packed = (unsigned int*)x1;           // E*4 = 12.8MB == x1 region (dense, no gaps);
                                                        // consumed by bucket_fill BEFORE agg1 writes x1
    unsigned char* hs2 = hs1;                           // fp8 [N][32] (hs1 dead after agg1)
    unsigned short* s13 = (unsigned short*)(hs1 + (size_t)N * 64);  // bf16 [N][16] in hs1 region back half
    unsigned char* hs3 = (unsigned char*)s02;           // fp8 [N][16] (s02 dead after agg2)

    // ---- weight prepack ----
    wpack_kernel<<<(112 * 128 + 255) / 256, 256, 0, stream>>>(W1, Ws02, Ws03, Wpk);

    // ---- CSR build (atomic-free 3-pass radix partition) ----
    histA_kernel<<<nblk, 256, 0, stream>>>(dst, E, counts);
    bscan2_kernel<<<NB, 256, 0, stream>>>(counts, nblk, blkoff, totals);
    bstart_kernel<<<1, NB, 0, stream>>>(totals, bstart, E);
    scatter_kernel<<<nblk, 256, 0, stream>>>(src, dst, E, bstart, blkoff, packed);
    bucket_fill_kernel<<<NB, 512, 0, stream>>>(packed, bstart, N, E, rowptr, col, dinv);

    int gb = (N + 63) / 64;
    // layer 1: one x pass via MFMA (2 tiles/wave) -> hs1 (fp8 [N][64]), s02, s03 (bf16)
    mfma3_kernel<<<(N + 127) / 128, 256, 0, stream>>>(x, Wpk, dinv, bs02, bs03, hs1, s02, s03, N);
    // agg 1 -> x1 (bf16)
    agg_kernel<64, 8, true><<<(N + 31) / 32, 256, 0, stream>>>(hs1, rowptr, col, dinv, b1, nullptr, nullptr, x1, N);
    // layer 2: one x1 pass -> hs2 (scaled fp8), s13 (bf16)
    gemm2b_kernel<64, 32, 16><<<gb, 256, 0, stream>>>(x1, W2, dinv, Ws13, bs13, hs2, s13, N);
    // agg 2 -> x2 (bf16), skip s02
    agg_kernel<32, 8, true><<<gb, 256, 0, stream>>>(hs2, rowptr, col, dinv, b2, s02, nullptr, x2, N);
    // layer 3
    gemm_l3_kernel<<<gb, 256, 0, stream>>>(x2, W3, dinv, hs3, N);
    // agg 3 -> out (fp32), skips s03 + s13
    agg_kernel<16, 4, false><<<gb, 256, 0, stream>>>(hs3, rowptr, col, dinv, b3, s03, s13, (float*)d_out, N);
}

// Round 16
// 208.027 us; speedup vs baseline: 1.0646x; 1.0646x over previous
//
#include <hip/hip_runtime.h>

#define NN 100000
#define NB 256            // buckets
#define NPB 391           // nodes per bucket: ceil(100000/256)=391; local dst fits in 9 bits
#define MSCH 4096         // edges per block for hist/scatter

__device__ inline unsigned short f2bf(float f) {
    unsigned u = __float_as_uint(f);
    return (unsigned short)((u + 0x7FFFu + ((u >> 16) & 1u)) >> 16);
}
__device__ inline unsigned packbf(float a, float b) {
    return (unsigned)f2bf(a) | ((unsigned)f2bf(b) << 16);
}
__device__ inline float bflo(unsigned u) { return __uint_as_float(u << 16); }
__device__ inline float bfhi(unsigned u) { return __uint_as_float(u & 0xFFFF0000u); }
__device__ inline float4 bf4(uint2 u) {
    return make_float4(bflo(u.x), bfhi(u.x), bflo(u.y), bfhi(u.y));
}

// ---- fp8 e4m3 (hardware cvt; encode+decode same HW format -> consistent) ----
__device__ inline void fp8acc(unsigned u, float4& a) {
    auto lo = __builtin_amdgcn_cvt_pk_f32_fp8((int)u, false);
    auto hi = __builtin_amdgcn_cvt_pk_f32_fp8((int)u, true);
    a.x += lo[0]; a.y += lo[1]; a.z += hi[0]; a.w += hi[1];
}
__device__ inline unsigned char f2fp8(float v) {
    return (unsigned char)(__builtin_amdgcn_cvt_pk_fp8_f32(v, 0.f, 0, false) & 0xFF);
}
__device__ inline unsigned short f2fp8x2(float a, float b) {
    return (unsigned short)(__builtin_amdgcn_cvt_pk_fp8_f32(a, b, 0, false) & 0xFFFF);
}

typedef __attribute__((ext_vector_type(8))) short bf16x8;
typedef __attribute__((ext_vector_type(4))) float f32x4;

// ---------------- CSR build: atomic-free radix partition with LDS-sorted scatter ----------------

// pass A: per-block bucket histogram -> counts[blk][NB]
__global__ __launch_bounds__(256) void histA_kernel(const int* __restrict__ dst, int E,
                                                    int* __restrict__ counts) {
    __shared__ int h[NB];
    int t = threadIdx.x, blk = blockIdx.x;
    h[t] = 0;
    __syncthreads();
    long c0 = (long)blk * MSCH;
    int nE = (int)min((long)MSCH, E - c0);
    for (int k = t; k < nE; k += 256)
        atomicAdd(&h[dst[c0 + k] / NPB], 1);
    __syncthreads();
    counts[(size_t)blk * NB + t] = h[t];
}

// pass B1: per-bucket exclusive scan across blocks -> blkoff, totals
__global__ __launch_bounds__(256) void bscan2_kernel(const int* __restrict__ counts, int nblk,
                                                     int* __restrict__ blkoff, int* __restrict__ totals) {
    int b = blockIdx.x, t = threadIdx.x;
    const int NP = 4;                 // ceil(nblk/256) for nblk<=1024
    int c[NP];
    int s = 0;
    #pragma unroll
    for (int q = 0; q < NP; ++q) {
        int j = t * NP + q;
        c[q] = (j < nblk) ? counts[(size_t)j * NB + b] : 0;
        s += c[q];
    }
    __shared__ int sh[256];
    sh[t] = s;
    __syncthreads();
    for (int off = 1; off < 256; off <<= 1) {
        int u = (t >= off) ? sh[t - off] : 0;
        __syncthreads();
        sh[t] += u;
        __syncthreads();
    }
    int base = sh[t] - s;
    int run = base;
    #pragma unroll
    for (int q = 0; q < NP; ++q) {
        int j = t * NP + q;
        if (j < nblk) blkoff[(size_t)j * NB + b] = run;
        run += c[q];
    }
    if (t == 255) totals[b] = sh[255];
}

// pass B2: 1-block exclusive scan of bucket totals -> bstart
__global__ __launch_bounds__(NB) void bstart_kernel(const int* __restrict__ totals, int* __restrict__ bstart, int E) {
    __shared__ int sh[NB];
    int t = threadIdx.x;
    int v = totals[t];
    sh[t] = v;
    __syncthreads();
    for (int off = 1; off < NB; off <<= 1) {
        int u = (t >= off) ? sh[t - off] : 0;
        __syncthreads();
        sh[t] += u;
        __syncthreads();
    }
    bstart[t] = sh[t] - v;
    if (t == NB - 1) bstart[NB] = E;
}

// pass C: LDS-sorted scatter. Per block: scan its counts row -> local offsets; rank edges
// into a bucket-sorted LDS buffer; then sweep linearly, emitting each bucket-run as a
// contiguous burst at bstart+blkoff (no global atomics; line-dense writes).
__global__ __launch_bounds__(256) void scatter_kernel(const int* __restrict__ src, const int* __restrict__ dst,
                                                      int E, const int* __restrict__ bstart,
                                                      const int* __restrict__ blkoff,
                                                      const int* __restrict__ counts,
                                                      unsigned int* __restrict__ packed) {
    __shared__ unsigned sorted[MSCH];        // 16 KB
    __shared__ unsigned char sortedb[MSCH];  // 4 KB
    __shared__ int sh[NB];
    __shared__ int lofs[NB];
    __shared__ int lofs0[NB];
    __shared__ int gbase[NB];
    int t = threadIdx.x, blk = blockIdx.x;

    int c = counts[(size_t)blk * NB + t];
    sh[t] = c;
    __syncthreads();
    for (int off = 1; off < NB; off <<= 1) {
        int u = (t >= off) ? sh[t - off] : 0;
        __syncthreads();
        sh[t] += u;
        __syncthreads();
    }
    lofs0[t] = sh[t] - c;
    lofs[t]  = sh[t] - c;
    gbase[t] = bstart[t] + blkoff[(size_t)blk * NB + t];
    __syncthreads();

    long c0 = (long)blk * MSCH;
    int nE = (int)min((long)MSCH, E - c0);
    for (int k = t; k < nE; k += 256) {
        int d = dst[c0 + k];
        int s = src[c0 + k];
        int b = d / NPB;
        int ld = d - b * NPB;
        int r = atomicAdd(&lofs[b], 1);
        sorted[r] = ((unsigned)s << 9) | (unsigned)ld;
        sortedb[r] = (unsigned char)b;
    }
    __syncthreads();
    for (int k = t; k < nE; k += 256) {
        int b = sortedb[k];
        packed[gbase[b] + (k - lofs0[b])] = sorted[k];
    }
}

// one block (512 thr) per bucket: LDS hist+scan over NPB local nodes -> rowptr/dinv, cursor fill -> col
__global__ __launch_bounds__(512) void bucket_fill_kernel(const unsigned int* __restrict__ packed,
                                                          const int* __restrict__ bstart, int N, int E,
                                                          int* __restrict__ rowptr, int* __restrict__ col,
                                                          float* __restrict__ dinv) {
    int b = blockIdx.x, t = threadIdx.x;
    int e0 = bstart[b], cnt = bstart[b + 1] - e0;
    __shared__ int hist[512];
    __shared__ int sh[512];
    __shared__ int cur[512];
    hist[t] = 0;
    __syncthreads();
    for (int e = t; e < cnt; e += 512)
        atomicAdd(&hist[packed[e0 + e] & 511u], 1);
    __syncthreads();
    int v = hist[t];
    sh[t] = v;
    __syncthreads();
    for (int off = 1; off < 512; off <<= 1) {
        int u = (t >= off) ? sh[t - off] : 0;
        __syncthreads();
        sh[t] += u;
        __syncthreads();
    }
    int ex = sh[t] - v;
    int node = b * NPB + t;
    if (t < NPB && node < N) {
        rowptr[node] = e0 + ex;
        dinv[node] = rsqrtf(1.0f + (float)v);
    }
    cur[t] = e0 + ex;
    __syncthreads();
    for (int e = t; e < cnt; e += 512) {
        unsigned int p = packed[e0 + e];
        int pos = atomicAdd(&cur[p & 511u], 1);
        col[pos] = (int)(p >> 9);
    }
    if (b == 0 && t == 0) rowptr[N] = E;
}

// ---------------- layer-1 weight prepack: Wpk[c][k] = bf16(W^T) ----

__global__ __launch_bounds__(256) void wpack_kernel(const float* __restrict__ W1, const float* __restrict__ Ws02,
                                                    const float* __restrict__ Ws03, unsigned short* __restrict__ Wpk) {
    int i = blockIdx.x * 256 + threadIdx.x;
    if (i >= 112 * 128) return;
    int c = i >> 7, k = i & 127;
    float v;
    if (c < 64)      v = W1[k * 64 + c];
    else if (c < 96) v = Ws02[k * 32 + (c - 64)];
    else             v = Ws03[k * 16 + (c - 96)];
    Wpk[i] = f2bf(v);
}

// ---------------- mfma3: one x pass -> hs1 ([N][64] fp8, scaled), s02 (32, bias, bf16), s03 (16, bias, bf16) ----

__global__ __launch_bounds__(256) void mfma3_kernel(const float* __restrict__ X,
        const unsigned short* __restrict__ Wpk, const float* __restrict__ scale,
        const float* __restrict__ bb, const float* __restrict__ bc,
        unsigned char* __restrict__ oa, unsigned short* __restrict__ ob,
        unsigned short* __restrict__ oc, int N) {
    int t = threadIdx.x;
    int wv = t >> 6, l = t & 63;
    int r0 = blockIdx.x * 128 + wv * 32;
    int col = l & 15, g = l >> 4;
    int rowA0 = r0 + col, rowA1 = r0 + 16 + col;
    bool ok0 = rowA0 < N, ok1 = rowA1 < N;
    const float* xr0 = X + (size_t)rowA0 * 128;
    const float* xr1 = X + (size_t)rowA1 * 128;

    f32x4 acc[2][7];
    #pragma unroll
    for (int ti = 0; ti < 2; ++ti)
        #pragma unroll
        for (int i = 0; i < 7; ++i) acc[ti][i] = (f32x4){0.f, 0.f, 0.f, 0.f};

    #pragma unroll
    for (int s = 0; s < 4; ++s) {
        int k0 = s * 32 + g * 8;
        float4 lo0 = ok0 ? *(const float4*)(xr0 + k0)     : make_float4(0.f, 0.f, 0.f, 0.f);
        float4 hi0 = ok0 ? *(const float4*)(xr0 + k0 + 4) : make_float4(0.f, 0.f, 0.f, 0.f);
        float4 lo1 = ok1 ? *(const float4*)(xr1 + k0)     : make_float4(0.f, 0.f, 0.f, 0.f);
        float4 hi1 = ok1 ? *(const float4*)(xr1 + k0 + 4) : make_float4(0.f, 0.f, 0.f, 0.f);
        union { bf16x8 v; unsigned u[4]; } A0, A1;
        A0.u[0] = packbf(lo0.x, lo0.y); A0.u[1] = packbf(lo0.z, lo0.w);
        A0.u[2] = packbf(hi0.x, hi0.y); A0.u[3] = packbf(hi0.z, hi0.w);
        A1.u[0] = packbf(lo1.x, lo1.y); A1.u[1] = packbf(lo1.z, lo1.w);
        A1.u[2] = packbf(hi1.x, hi1.y); A1.u[3] = packbf(hi1.z, hi1.w);
        #pragma unroll
        for (int ct = 0; ct < 7; ++ct) {
            bf16x8 B = *(const bf16x8*)(Wpk + ((size_t)(ct * 16 + col) * 128 + k0));
            acc[0][ct] = __builtin_amdgcn_mfma_f32_16x16x32_bf16(A0.v, B, acc[0][ct], 0, 0, 0);
            acc[1][ct] = __builtin_amdgcn_mfma_f32_16x16x32_bf16(A1.v, B, acc[1][ct], 0, 0, 0);
        }
    }

    #pragma unroll
    for (int ti = 0; ti < 2; ++ti) {
        #pragma unroll
        for (int v = 0; v < 4; ++v) {
            int row = r0 + ti * 16 + g * 4 + v;
            if (row < N) {
                float sc = scale[row];
                #pragma unroll
                for (int ct = 0; ct < 4; ++ct)
                    oa[(size_t)row * 64 + ct * 16 + col] = f2fp8(acc[ti][ct][v] * sc);
                #pragma unroll
                for (int ct = 4; ct < 6; ++ct) {
                    int c2 = (ct - 4) * 16 + col;
                    ob[(size_t)row * 32 + c2] = f2bf(acc[ti][ct][v] + bb[c2]);
                }
                oc[(size_t)row * 16 + col] = f2bf(acc[ti][6][v] + bc[col]);
            }
        }
    }
}

// ---------------- gemm2b: bf16 X input -> hs2 (fp8, scaled), s13 (bf16, bias) ----------------

template <int K, int C1, int C2>
__global__ __launch_bounds__(256) void gemm2b_kernel(const unsigned short* __restrict__ X,
        const float* __restrict__ Wa, const float* __restrict__ scale,
        const float* __restrict__ Wb, const float* __restrict__ bb,
        unsigned char* __restrict__ oa, unsigned short* __restrict__ ob, int N) {
    constexpr int M1 = C1 / 16, M2 = C2 / 16;
    constexpr int XS = K + 6;
    __shared__ float XL[64 * XS];
    __shared__ float WLa[K * C1];
    __shared__ float WLb[K * C2];
    int t = threadIdx.x;
    int r0 = blockIdx.x * 64;

    for (int i = t; i < K * C1 / 4; i += 256) ((float4*)WLa)[i] = ((const float4*)Wa)[i];
    for (int i = t; i < K * C2 / 4; i += 256) ((float4*)WLb)[i] = ((const float4*)Wb)[i];
    for (int i = t; i < 64 * (K / 4); i += 256) {
        int row = i / (K / 4), g = i % (K / 4);
        uint2 u = make_uint2(0u, 0u);
        if (r0 + row < N) u = ((const uint2*)(X + (size_t)(r0 + row) * K))[g];
        float* p = &XL[row * XS + g * 4];
        *(float2*)p = make_float2(bflo(u.x), bfhi(u.x));
        *(float2*)(p + 2) = make_float2(bflo(u.y), bfhi(u.y));
    }
    __syncthreads();

    int ty = t >> 4, tx = t & 15;
    float acc1[4][M1] = {}, acc2[4][M2] = {};
    const float* xb = &XL[(ty * 4) * XS];
    const float* wba = &WLa[tx * M1];
    const float* wbb = &WLb[tx * M2];
    for (int k = 0; k < K; ++k) {
        float x0 = xb[k], x1 = xb[XS + k], x2 = xb[2 * XS + k], x3 = xb[3 * XS + k];
        float wa[M1], wb2[M2];
        #pragma unroll
        for (int j = 0; j < M1; ++j) wa[j] = wba[k * C1 + j];
        #pragma unroll
        for (int j = 0; j < M2; ++j) wb2[j] = wbb[k * C2 + j];
        #pragma unroll
        for (int j = 0; j < M1; ++j) {
            acc1[0][j] = fmaf(x0, wa[j], acc1[0][j]);
            acc1[1][j] = fmaf(x1, wa[j], acc1[1][j]);
            acc1[2][j] = fmaf(x2, wa[j], acc1[2][j]);
            acc1[3][j] = fmaf(x3, wa[j], acc1[3][j]);
        }
        #pragma unroll
        for (int j = 0; j < M2; ++j) {
            acc2[0][j] = fmaf(x0, wb2[j], acc2[0][j]);
            acc2[1][j] = fmaf(x1, wb2[j], acc2[1][j]);
            acc2[2][j] = fmaf(x2, wb2[j], acc2[2][j]);
            acc2[3][j] = fmaf(x3, wb2[j], acc2[3][j]);
        }
    }

    #pragma unroll
    for (int i = 0; i < 4; ++i) {
        int row = r0 + ty * 4 + i;
        if (row < N) {
            float sc = scale[row];
            *(unsigned short*)(oa + (size_t)row * C1 + tx * 2) = f2fp8x2(acc1[i][0] * sc, acc1[i][1] * sc);
            ob[(size_t)row * C2 + tx] = f2bf(acc2[i][0] + bb[tx]);
        }
    }
}

// ---------------- gemm_l3: bf16 X [N][32] -> hs3 [N][16] fp8, scaled ----------------

__global__ __launch_bounds__(256) void gemm_l3_kernel(const unsigned short* __restrict__ X,
        const float* __restrict__ W, const float* __restrict__ scale,
        unsigned char* __restrict__ out, int N) {
    constexpr int K = 32, C = 16, XS = K + 6;
    __shared__ float XL[64 * XS];
    __shared__ float WL[K * C];
    int t = threadIdx.x;
    int r0 = blockIdx.x * 64;

    for (int i = t; i < K * C / 4; i += 256) ((float4*)WL)[i] = ((const float4*)W)[i];
    for (int i = t; i < 64 * (K / 4); i += 256) {
        int row = i / (K / 4), g = i % (K / 4);
        uint2 u = make_uint2(0u, 0u);
        if (r0 + row < N) u = ((const uint2*)(X + (size_t)(r0 + row) * K))[g];
        float* p = &XL[row * XS + g * 4];
        *(float2*)p = make_float2(bflo(u.x), bfhi(u.x));
        *(float2*)(p + 2) = make_float2(bflo(u.y), bfhi(u.y));
    }
    __syncthreads();

    int ty = t >> 4, tx = t & 15;
    float acc[4] = {0.f, 0.f, 0.f, 0.f};
    const float* xb = &XL[(ty * 4) * XS];
    for (int k = 0; k < K; ++k) {
        float wv = WL[k * C + tx];
        acc[0] = fmaf(xb[k], wv, acc[0]);
        acc[1] = fmaf(xb[XS + k], wv, acc[1]);
        acc[2] = fmaf(xb[2 * XS + k], wv, acc[2]);
        acc[3] = fmaf(xb[3 * XS + k], wv, acc[3]);
    }
    #pragma unroll
    for (int i = 0; i < 4; ++i) {
        int row = r0 + ty * 4 + i;
        if (row < N) out[(size_t)row * C + tx] = f2fp8(acc[i] * scale[row]);
    }
}

// ---------------- Aggregation (fp8 hs gather) ----------------

template <int F, int FPL, bool OBF>
__global__ __launch_bounds__(256) void agg_kernel(const unsigned char* __restrict__ hs,
        const int* __restrict__ rowptr, const int* __restrict__ col,
        const float* __restrict__ dinv, const float* __restrict__ bias,
        const unsigned short* __restrict__ skipA, const unsigned short* __restrict__ skipB,
        void* __restrict__ outv, int N) {
    constexpr int VL = F / FPL;
    constexpr int NPW = 64 / VL;
    constexpr int W = 8;
    constexpr int CR = W / VL;
    int t = threadIdx.x;
    int lane = t & 63, wv = t >> 6;
    int sub = lane / VL, fq = lane % VL;
    int i = (blockIdx.x * 4 + wv) * NPW + sub;
    if (i >= N) return;

    float4 aA0 = make_float4(0.f, 0.f, 0.f, 0.f);
    float4 aA1 = make_float4(0.f, 0.f, 0.f, 0.f);
    float4 aB0 = make_float4(0.f, 0.f, 0.f, 0.f);
    float4 aB1 = make_float4(0.f, 0.f, 0.f, 0.f);

    {
        const unsigned char* hrow = hs + (size_t)i * F + fq * FPL;
        if constexpr (FPL == 8) {
            uint2 u = *(const uint2*)hrow;
            fp8acc(u.x, aA0); fp8acc(u.y, aB0);
        } else {
            fp8acc(*(const unsigned*)hrow, aA0);
        }
    }

    int p0 = rowptr[i], p1 = rowptr[i + 1];
    int p = p0;
    for (; p + W <= p1; p += W) {
        int cw[CR];
        #pragma unroll
        for (int j = 0; j < CR; ++j) cw[j] = col[p + fq + j * VL];
        #pragma unroll
        for (int k = 0; k < W; ++k) {
            int s = __shfl(cw[k / VL], k % VL, VL);
            const unsigned char* sp = hs + (size_t)s * F + fq * FPL;
            if constexpr (FPL == 8) {
                uint2 u = *(const uint2*)sp;
                if (k & 1) { fp8acc(u.x, aA1); fp8acc(u.y, aB1); }
                else       { fp8acc(u.x, aA0); fp8acc(u.y, aB0); }
            } else {
                if (k & 1) fp8acc(*(const unsigned*)sp, aA1);
                else       fp8acc(*(const unsigned*)sp, aA0);
            }
        }
    }
    for (; p < p1; p += VL) {
        int c = (p + fq < p1) ? col[p + fq] : 0;
        int m = min(VL, p1 - p);
        for (int k = 0; k < m; ++k) {
            int s = __shfl(c, k, VL);
            const unsigned char* sp = hs + (size_t)s * F + fq * FPL;
            if constexpr (FPL == 8) {
                uint2 u = *(const uint2*)sp;
                fp8acc(u.x, aA1); fp8acc(u.y, aB1);
            } else {
                fp8acc(*(const unsigned*)sp, aA1);
            }
        }
    }

    float di = dinv[i];
    int fb = fq * FPL;
    float o[FPL];
    o[0] = fmaxf(di * (aA0.x + aA1.x) + bias[fb + 0], 0.f);
    o[1] = fmaxf(di * (aA0.y + aA1.y) + bias[fb + 1], 0.f);
    o[2] = fmaxf(di * (aA0.z + aA1.z) + bias[fb + 2], 0.f);
    o[3] = fmaxf(di * (aA0.w + aA1.w) + bias[fb + 3], 0.f);
    if constexpr (FPL == 8) {
        o[4] = fmaxf(di * (aB0.x + aB1.x) + bias[fb + 4], 0.f);
        o[5] = fmaxf(di * (aB0.y + aB1.y) + bias[fb + 5], 0.f);
        o[6] = fmaxf(di * (aB0.z + aB1.z) + bias[fb + 6], 0.f);
        o[7] = fmaxf(di * (aB0.w + aB1.w) + bias[fb + 7], 0.f);
    }
    if (skipA) {
        const unsigned short* sp = skipA + (size_t)i * F + fb;
        if constexpr (FPL == 8) {
            uint4 sa = *(const uint4*)sp;
            float4 s0 = bf4(make_uint2(sa.x, sa.y)), s1 = bf4(make_uint2(sa.z, sa.w));
            o[0] += s0.x; o[1] += s0.y; o[2] += s0.z; o[3] += s0.w;
            o[4] += s1.x; o[5] += s1.y; o[6] += s1.z; o[7] += s1.w;
        } else {
            float4 s0 = bf4(*(const uint2*)sp);
            o[0] += s0.x; o[1] += s0.y; o[2] += s0.z; o[3] += s0.w;
        }
    }
    if (skipB) {
        const unsigned short* sp = skipB + (size_t)i * F + fb;
        if constexpr (FPL == 8) {
            uint4 sa = *(const uint4*)sp;
            float4 s0 = bf4(make_uint2(sa.x, sa.y)), s1 = bf4(make_uint2(sa.z, sa.w));
            o[0] += s0.x; o[1] += s0.y; o[2] += s0.z; o[3] += s0.w;
            o[4] += s1.x; o[5] += s1.y; o[6] += s1.z; o[7] += s1.w;
        } else {
            float4 s0 = bf4(*(const uint2*)sp);
            o[0] += s0.x; o[1] += s0.y; o[2] += s0.z; o[3] += s0.w;
        }
    }

    if constexpr (OBF) {
        unsigned short* op = (unsigned short*)outv + (size_t)i * F + fb;
        if constexpr (FPL == 8) {
            uint4 w4;
            w4.x = packbf(o[0], o[1]); w4.y = packbf(o[2], o[3]);
            w4.z = packbf(o[4], o[5]); w4.w = packbf(o[6], o[7]);
            *(uint4*)op = w4;
        } else {
            uint2 w2;
            w2.x = packbf(o[0], o[1]); w2.y = packbf(o[2], o[3]);
            *(uint2*)op = w2;
        }
    } else {
        *(float4*)((float*)outv + (size_t)i * F + fb) = make_float4(o[0], o[1], o[2], o[3]);
    }
}

// ---------------- launch ----------------

extern "C" void kernel_launch(void* const* d_in, const int* in_sizes, int n_in,
                              void* d_out, int out_size, void* d_ws, size_t ws_size,
                              hipStream_t stream) {
    const int N = NN;
    const float* x   = (const float*)d_in[0];
    const int*   ei  = (const int*)d_in[1];
    const int    E   = in_sizes[1] / 2;
    const int*   src = ei;
    const int*   dst = ei + E;
    const float* W1 = (const float*)d_in[2],  *b1  = (const float*)d_in[3];
    const float* W2 = (const float*)d_in[4],  *b2  = (const float*)d_in[5];
    const float* W3 = (const float*)d_in[6],  *b3  = (const float*)d_in[7];
    const float* Ws02 = (const float*)d_in[8],  *bs02 = (const float*)d_in[9];
    const float* Ws03 = (const float*)d_in[10], *bs03 = (const float*)d_in[11];
    const float* Ws13 = (const float*)d_in[12], *bs13 = (const float*)d_in[13];

    const int nblk = (E + MSCH - 1) / MSCH;   // 782 for E=3.2M

    char* w = (char*)d_ws;
    size_t off = 0;
    auto alloc = [&](size_t bytes) -> void* {
        void* p = w + off;
        off += (bytes + 255) & ~(size_t)255;
        return p;
    };
    int*   bstart   = (int*)alloc((size_t)(NB + 1) * 4);
    int*   totals   = (int*)alloc((size_t)NB * 4);
    int*   rowptr   = (int*)alloc(((size_t)N + 1) * 4);
    float* dinv     = (float*)alloc((size_t)N * 4);
    int*   col      = (int*)alloc((size_t)E * 4);
    int*   counts   = (int*)alloc((size_t)nblk * NB * 4);   // 800 KB
    int*   blkoff   = (int*)alloc((size_t)nblk * NB * 4);   // 800 KB
    unsigned short* Wpk = (unsigned short*)alloc((size_t)112 * 128 * 2);
    unsigned char* hs1  = (unsigned char*)alloc((size_t)N * 64 * 2);    // fp8 [N][64] in first N*64 bytes
    unsigned short* x1  = (unsigned short*)alloc((size_t)N * 64 * 2);   // bf16 [N][64]
    unsigned short* s02 = (unsigned short*)alloc((size_t)N * 32 * 2);   // bf16 [N][32]
    unsigned short* s03 = (unsigned short*)alloc((size_t)N * 16 * 2);   // bf16 [N][16]
    unsigned short* x2  = (unsigned short*)alloc((size_t)N * 32 * 2);   // bf16 [N][32]
    // aliases over dead regions
    unsigned int* packed = (unsigned int*)x1;           // E*4 = 12.8MB == x1 region (dense);
                                                        // consumed by bucket_fill BEFORE agg1 writes x1
    unsigned char* hs2 = hs1;                           // fp8 [N][32] (hs1 dead after agg1)
    unsigned short* s13 = (unsigned short*)(hs1 + (size_t)N * 64);  // bf16 [N][16] in hs1 region back half
    unsigned char* hs3 = (unsigned char*)s02;           // fp8 [N][16] (s02 dead after agg2)

    // ---- weight prepack ----
    wpack_kernel<<<(112 * 128 + 255) / 256, 256, 0, stream>>>(W1, Ws02, Ws03, Wpk);

    // ---- CSR build (atomic-free radix partition, LDS-sorted scatter) ----
    histA_kernel<<<nblk, 256, 0, stream>>>(dst, E, counts);
    bscan2_kernel<<<NB, 256, 0, stream>>>(counts, nblk, blkoff, totals);
    bstart_kernel<<<1, NB, 0, stream>>>(totals, bstart, E);
    scatter_kernel<<<nblk, 256, 0, stream>>>(src, dst, E, bstart, blkoff, counts, packed);
    bucket_fill_kernel<<<NB, 512, 0, stream>>>(packed, bstart, N, E, rowptr, col, dinv);

    int gb = (N + 63) / 64;
    // layer 1: one x pass via MFMA (2 tiles/wave) -> hs1 (fp8 [N][64]), s02, s03 (bf16)
    mfma3_kernel<<<(N + 127) / 128, 256, 0, stream>>>(x, Wpk, dinv, bs02, bs03, hs1, s02, s03, N);
    // agg 1 -> x1 (bf16)
    agg_kernel<64, 8, true><<<(N + 31) / 32, 256, 0, stream>>>(hs1, rowptr, col, dinv, b1, nullptr, nullptr, x1, N);
    // layer 2: one x1 pass -> hs2 (scaled fp8), s13 (bf16)
    gemm2b_kernel<64, 32, 16><<<gb, 256, 0, stream>>>(x1, W2, dinv, Ws13, bs13, hs2, s13, N);
    // agg 2 -> x2 (bf16), skip s02
    agg_kernel<32, 8, true><<<gb, 256, 0, stream>>>(hs2, rowptr, col, dinv, b2, s02, nullptr, x2, N);
    // layer 3
    gemm_l3_kernel<<<gb, 256, 0, stream>>>(x2, W3, dinv, hs3, N);
    // agg 3 -> out (fp32), skips s03 + s13
    agg_kernel<16, 4, false><<<gb, 256, 0, stream>>>(hs3, rowptr, col, dinv, b3, s03, s13, (float*)d_out, N);
}